// Round 1
// baseline (943.418 us; speedup 1.0000x reference)
//
#include <hip/hip_runtime.h>
#include <math.h>

#define NVOX 50000
#define PPTS 32
#define CIN 4
#define HDIM 64
#define ODIM 128
#define EPSBN 1e-5f

__global__ __launch_bounds__(256, 2) void vfe_kernel(
    const float* __restrict__ vf, const int* __restrict__ vnp,
    const float* __restrict__ W1, const float* __restrict__ b1,
    const float* __restrict__ g1, const float* __restrict__ be1,
    const float* __restrict__ m1, const float* __restrict__ v1,
    const float* __restrict__ W2, const float* __restrict__ b2,
    const float* __restrict__ g2, const float* __restrict__ be2,
    const float* __restrict__ m2, const float* __restrict__ v2,
    const float* __restrict__ W3, const float* __restrict__ b3,
    float* __restrict__ out)
{
    // LDS: folded weights. All arrays 16B aligned.
    __shared__ __align__(16) float sW1f[CIN * HDIM];   // [i][j], 256
    __shared__ __align__(16) float sc1[HDIM];
    __shared__ __align__(16) float sW2f[HDIM * HDIM];  // [k][j], 4096
    __shared__ __align__(16) float sc2[HDIM];
    __shared__ __align__(16) float sW3[HDIM * ODIM];   // [k][o], 8192
    __shared__ __align__(16) float sb3[ODIM];
    __shared__ __align__(16) float ss1[HDIM];
    __shared__ __align__(16) float ss2[HDIM];

    const int tid = threadIdx.x;

    // ---- phase 0: scales / folded biases ----
    if (tid < 64) {
        float s = g1[tid] * rsqrtf(v1[tid] + EPSBN);
        ss1[tid] = s;
        sc1[tid] = (b1[tid] - m1[tid]) * s + be1[tid];
    } else if (tid < 128) {
        int t = tid - 64;
        float s = g2[t] * rsqrtf(v2[t] + EPSBN);
        ss2[t] = s;
        sc2[t] = (b2[t] - m2[t]) * s + be2[t];
    } else {
        int t = tid - 128;   // 0..127
        sb3[t] = b3[t];
    }
    __syncthreads();

    // ---- phase 1: fold weights into LDS ----
    // W1f: 256 elems, 1 per thread
    {
        int e = tid;                 // e = i*64 + j
        sW1f[e] = W1[e] * ss1[e & 63];
    }
    // W2f: 4096 elems, 16 per thread
    for (int e = tid; e < HDIM * HDIM; e += 256) {
        sW2f[e] = W2[e] * ss2[e & 63];
    }
    // W3: plain copy, float4
    {
        const float4* src = (const float4*)W3;
        float4* dst = (float4*)sW3;
        for (int e = tid; e < (HDIM * ODIM) / 4; e += 256) dst[e] = src[e];
    }
    __syncthreads();

    // ---- per-thread point ----
    const int pt = blockIdx.x * 256 + tid;       // 0 .. 1.6M-1
    const int vox = pt >> 5;
    const int slot = pt & 31;
    const float4 x = *(const float4*)(vf + (size_t)pt * 4);
    const int n = vnp[vox];
    const bool valid = slot < n;

    // layer 1: h1 = relu(x @ W1f + c1)
    float h1[HDIM];
    {
        const float4* W1v = (const float4*)sW1f;   // [i*16 + jc]
        const float4* c1v = (const float4*)sc1;
#pragma unroll
        for (int jc = 0; jc < 16; ++jc) {
            float4 w0 = W1v[jc];
            float4 w1 = W1v[16 + jc];
            float4 w2 = W1v[32 + jc];
            float4 w3 = W1v[48 + jc];
            float4 a = c1v[jc];
            a.x = fmaf(x.x, w0.x, fmaf(x.y, w1.x, fmaf(x.z, w2.x, fmaf(x.w, w3.x, a.x))));
            a.y = fmaf(x.x, w0.y, fmaf(x.y, w1.y, fmaf(x.z, w2.y, fmaf(x.w, w3.y, a.y))));
            a.z = fmaf(x.x, w0.z, fmaf(x.y, w1.z, fmaf(x.z, w2.z, fmaf(x.w, w3.z, a.z))));
            a.w = fmaf(x.x, w0.w, fmaf(x.y, w1.w, fmaf(x.z, w2.w, fmaf(x.w, w3.w, a.w))));
            h1[4 * jc + 0] = fmaxf(a.x, 0.f);
            h1[4 * jc + 1] = fmaxf(a.y, 0.f);
            h1[4 * jc + 2] = fmaxf(a.z, 0.f);
            h1[4 * jc + 3] = fmaxf(a.w, 0.f);
        }
    }

    // layer 2: h2 = relu(h1 @ W2f + c2)   (fully unrolled: h1/h2 must stay in regs)
    float h2[HDIM];
    {
        const float4* W2v = (const float4*)sW2f;   // [k*16 + jc]
        const float4* c2v = (const float4*)sc2;
#pragma unroll
        for (int jc = 0; jc < 16; ++jc) {
            float4 acc = c2v[jc];
#pragma unroll
            for (int k = 0; k < HDIM; ++k) {
                float4 w = W2v[k * 16 + jc];
                float hk = h1[k];
                acc.x = fmaf(hk, w.x, acc.x);
                acc.y = fmaf(hk, w.y, acc.y);
                acc.z = fmaf(hk, w.z, acc.z);
                acc.w = fmaf(hk, w.w, acc.w);
            }
            h2[4 * jc + 0] = fmaxf(acc.x, 0.f);
            h2[4 * jc + 1] = fmaxf(acc.y, 0.f);
            h2[4 * jc + 2] = fmaxf(acc.z, 0.f);
            h2[4 * jc + 3] = fmaxf(acc.w, 0.f);
        }
    }

    // layer 3 + masked max over the voxel's 32 lanes, 4 outputs per chunk
    {
        const float4* W3v = (const float4*)sW3;    // [k*32 + oc]
        const float4* b3v = (const float4*)sb3;
        float4* outp = (float4*)(out + (size_t)vox * ODIM);
        for (int oc = 0; oc < 32; ++oc) {          // rolled: keeps code size sane
            float4 acc = b3v[oc];
#pragma unroll
            for (int k = 0; k < HDIM; ++k) {
                float4 w = W3v[k * 32 + oc];
                float hk = h2[k];
                acc.x = fmaf(hk, w.x, acc.x);
                acc.y = fmaf(hk, w.y, acc.y);
                acc.z = fmaf(hk, w.z, acc.z);
                acc.w = fmaf(hk, w.w, acc.w);
            }
            if (!valid) {
                acc.x = -INFINITY; acc.y = -INFINITY;
                acc.z = -INFINITY; acc.w = -INFINITY;
            }
            // butterfly max over 32 lanes (wave holds 2 voxels; xor<32 stays in half)
#pragma unroll
            for (int msk = 1; msk <= 16; msk <<= 1) {
                acc.x = fmaxf(acc.x, __shfl_xor(acc.x, msk));
                acc.y = fmaxf(acc.y, __shfl_xor(acc.y, msk));
                acc.z = fmaxf(acc.z, __shfl_xor(acc.z, msk));
                acc.w = fmaxf(acc.w, __shfl_xor(acc.w, msk));
            }
            if (slot == 0) outp[oc] = acc;
        }
    }
}

extern "C" void kernel_launch(void* const* d_in, const int* in_sizes, int n_in,
                              void* d_out, int out_size, void* d_ws, size_t ws_size,
                              hipStream_t stream) {
    const float* vf  = (const float*)d_in[0];
    const int*   vnp = (const int*)d_in[1];
    const float* W1  = (const float*)d_in[2];
    const float* b1  = (const float*)d_in[3];
    const float* g1  = (const float*)d_in[4];
    const float* be1 = (const float*)d_in[5];
    const float* m1  = (const float*)d_in[6];
    const float* v1  = (const float*)d_in[7];
    const float* W2  = (const float*)d_in[8];
    const float* b2  = (const float*)d_in[9];
    const float* g2  = (const float*)d_in[10];
    const float* be2 = (const float*)d_in[11];
    const float* m2  = (const float*)d_in[12];
    const float* v2  = (const float*)d_in[13];
    const float* W3  = (const float*)d_in[14];
    const float* b3  = (const float*)d_in[15];
    float* out = (float*)d_out;

    const int blocks = (NVOX * PPTS) / 256;   // 6250
    vfe_kernel<<<blocks, 256, 0, stream>>>(vf, vnp, W1, b1, g1, be1, m1, v1,
                                           W2, b2, g2, be2, m2, v2, W3, b3, out);
}

// Round 2
// 210.881 us; speedup vs baseline: 4.4737x; 4.4737x over previous
//
#include <hip/hip_runtime.h>
#include <math.h>

#define NVOX 50000
#define PPTS 32
#define HDIM 64
#define ODIM 128
#define EPSBN 1e-5f

typedef _Float16 f16x8 __attribute__((ext_vector_type(8)));
typedef _Float16 f16x4 __attribute__((ext_vector_type(4)));
typedef float f32x4 __attribute__((ext_vector_type(4)));

// LDS row stride for all f16 weight/activation tiles: 80 f16 = 160 B.
// 160 B keeps rows 16B-aligned for ds_read_b128 and reduces the stride-128
// 16-way bank conflict to 4-way (~1.58x).
#define RS 80

__global__ __launch_bounds__(256, 2) void vfe_mfma(
    const float* __restrict__ vf, const int* __restrict__ vnp,
    const float* __restrict__ W1, const float* __restrict__ b1,
    const float* __restrict__ g1, const float* __restrict__ be1,
    const float* __restrict__ m1, const float* __restrict__ v1,
    const float* __restrict__ W2, const float* __restrict__ b2,
    const float* __restrict__ g2, const float* __restrict__ be2,
    const float* __restrict__ m2, const float* __restrict__ v2,
    const float* __restrict__ W3, const float* __restrict__ b3,
    float* __restrict__ out)
{
    // ---- LDS ----
    __shared__ __align__(16) _Float16 sW2T[HDIM * RS];   // [ch_out][ch_in] folded, f16
    __shared__ __align__(16) _Float16 sW3T[ODIM * RS];   // [o][ch_in] f16
    __shared__ __align__(16) _Float16 sW1c[HDIM * 8];    // [ch_out][w0..w3, c1, 0,0,0]
    __shared__ __align__(16) float ss2f[HDIM];
    __shared__ __align__(16) float sc2[HDIM];
    __shared__ __align__(16) float sb3[ODIM];
    __shared__ __align__(16) _Float16 sH[4][2][16 * RS]; // [wave][h1/h2][pt][ch]

    const int tid = threadIdx.x;

    // ---- phase 0: BN fold scalars + W1c rows + b3 copy ----
    if (tid < 64) {
        float s1 = g1[tid] * rsqrtf(v1[tid] + EPSBN);
        float c1 = (b1[tid] - m1[tid]) * s1 + be1[tid];
        _Float16* r = &sW1c[tid * 8];
        r[0] = (_Float16)(W1[0 * 64 + tid] * s1);
        r[1] = (_Float16)(W1[1 * 64 + tid] * s1);
        r[2] = (_Float16)(W1[2 * 64 + tid] * s1);
        r[3] = (_Float16)(W1[3 * 64 + tid] * s1);
        r[4] = (_Float16)c1;
        r[5] = (_Float16)0.0f; r[6] = (_Float16)0.0f; r[7] = (_Float16)0.0f;
    } else if (tid < 128) {
        int i = tid - 64;
        float s2 = g2[i] * rsqrtf(v2[i] + EPSBN);
        ss2f[i] = s2;
        sc2[i] = (b2[i] - m2[i]) * s2 + be2[i];
    } else {
        sb3[tid - 128] = b3[tid - 128];
    }
    __syncthreads();

    // ---- phase 1: stage W2 (folded, transposed) and W3 (transposed) as f16 ----
    for (int e = tid; e < HDIM * HDIM; e += 256) {
        int ch = e >> 6, chp = e & 63;                    // W2[ch][chp]
        sW2T[chp * RS + ch] = (_Float16)(W2[e] * ss2f[chp]);
    }
    for (int e = tid; e < HDIM * ODIM; e += 256) {
        int ch = e >> 7, o = e & 127;                     // W3[ch][o]
        sW3T[o * RS + ch] = (_Float16)W3[e];
    }
    __syncthreads();
    // no barriers beyond this point: all LDS traffic is wave-private

    const int wave = tid >> 6;
    const int lane = tid & 63;
    const int q    = lane >> 4;    // quad
    const int m16  = lane & 15;

    const int wavebase = blockIdx.x * 256 + wave * 64;   // first point of this wave
    const int voxA = wavebase >> 5;                      // wave covers voxels voxA, voxA+1
    const int nA = vnp[voxA];
    const int nB = vnp[voxA + 1];

    // ---- per-wave register preloads ----
    // A1 frags: W1c rows (q==0 carries data, k=0..3 weights, k=4 bias; else 0)
    f16x8 a1[4];
#pragma unroll
    for (int mt = 0; mt < 4; ++mt) {
        f16x8 t = *(const f16x8*)&sW1c[(m16 + 16 * mt) * 8];
        a1[mt] = (q == 0) ? t : (f16x8)0;
    }
    // A2 frags: A2[m=ch'][k=ch] = W2f[ch][ch'] = sW2T[ch'][ch]
    f16x8 a2[4][2];
#pragma unroll
    for (int mt = 0; mt < 4; ++mt)
#pragma unroll
        for (int kk = 0; kk < 2; ++kk)
            a2[mt][kk] = *(const f16x8*)&sW2T[(m16 + 16 * mt) * RS + kk * 32 + q * 8];
    // B3 frags: B3[k=ch][n=o] = W3[ch][o] = sW3T[o][ch]
    f16x8 b3f[8][2];
#pragma unroll
    for (int nt = 0; nt < 8; ++nt)
#pragma unroll
        for (int kk = 0; kk < 2; ++kk)
            b3f[nt][kk] = *(const f16x8*)&sW3T[(m16 + 16 * nt) * RS + kk * 32 + q * 8];
    // c2 for rows ch' = mt*16 + q*4 + reg (same addr across m16 -> broadcast)
    float4 c2v[4];
#pragma unroll
    for (int mt = 0; mt < 4; ++mt)
        c2v[mt] = *(const float4*)&sc2[mt * 16 + q * 4];
    // b3 for o = nt*16 + m16
    float b3r[8];
#pragma unroll
    for (int nt = 0; nt < 8; ++nt) b3r[nt] = sb3[nt * 16 + m16];

    _Float16* h1t = sH[wave][0];
    _Float16* h2t = sH[wave][1];

    // running voxel max: [nt_o][voxel 0/1]
    float vmax[8][2];
#pragma unroll
    for (int nt = 0; nt < 8; ++nt) { vmax[nt][0] = -INFINITY; vmax[nt][1] = -INFINITY; }

    // ---- main: 4 point-groups of 16 ----
    for (int ptg = 0; ptg < 4; ++ptg) {
        // B1 frag: x for pt = wavebase + ptg*16 + m16 (k=0..3 = x, k=4 = 1.0)
        const int pt = wavebase + ptg * 16 + m16;
        float4 xv = *(const float4*)(vf + (size_t)pt * 4);
        f16x8 b1 = (f16x8)0;
        if (q == 0) {
            b1[0] = (_Float16)xv.x; b1[1] = (_Float16)xv.y;
            b1[2] = (_Float16)xv.z; b1[3] = (_Float16)xv.w;
            b1[4] = (_Float16)1.0f;
        }

        // ---- layer 1 (transposed): D1[ch'][pt16] ----
#pragma unroll
        for (int mt = 0; mt < 4; ++mt) {
            f32x4 acc = {0.f, 0.f, 0.f, 0.f};
            acc = __builtin_amdgcn_mfma_f32_16x16x32_f16(a1[mt], b1, acc, 0, 0, 0);
            // lane holds rows ch' = mt*16 + q*4 + reg, col pt-local = m16
            f16x4 h;
            h[0] = (_Float16)fmaxf(acc[0], 0.f);
            h[1] = (_Float16)fmaxf(acc[1], 0.f);
            h[2] = (_Float16)fmaxf(acc[2], 0.f);
            h[3] = (_Float16)fmaxf(acc[3], 0.f);
            *(f16x4*)&h1t[m16 * RS + mt * 16 + q * 4] = h;
        }

        // ---- layer 2 (transposed): D2[ch'][pt16] ----
        f16x8 b2f[2];
#pragma unroll
        for (int kk = 0; kk < 2; ++kk)
            b2f[kk] = *(const f16x8*)&h1t[m16 * RS + kk * 32 + q * 8];
#pragma unroll
        for (int mt = 0; mt < 4; ++mt) {
            f32x4 acc = {0.f, 0.f, 0.f, 0.f};
            acc = __builtin_amdgcn_mfma_f32_16x16x32_f16(a2[mt][0], b2f[0], acc, 0, 0, 0);
            acc = __builtin_amdgcn_mfma_f32_16x16x32_f16(a2[mt][1], b2f[1], acc, 0, 0, 0);
            f16x4 h;
            h[0] = (_Float16)fmaxf(acc[0] + c2v[mt].x, 0.f);
            h[1] = (_Float16)fmaxf(acc[1] + c2v[mt].y, 0.f);
            h[2] = (_Float16)fmaxf(acc[2] + c2v[mt].z, 0.f);
            h[3] = (_Float16)fmaxf(acc[3] + c2v[mt].w, 0.f);
            *(f16x4*)&h2t[m16 * RS + mt * 16 + q * 4] = h;
        }

        // ---- layer 3 (normal): D3[pt16][o], A3 = h2 ----
        f16x8 a3[2];
#pragma unroll
        for (int kk = 0; kk < 2; ++kk)
            a3[kk] = *(const f16x8*)&h2t[m16 * RS + kk * 32 + q * 8];

        // validity mask for pts = wavebase + ptg*16 + q*4 + reg
        const int n = (ptg < 2) ? nA : nB;
        const int slotbase = (ptg & 1) * 16 + q * 4;
        float madd[4];
#pragma unroll
        for (int r = 0; r < 4; ++r)
            madd[r] = (slotbase + r < n) ? 0.f : -INFINITY;
        const int v = ptg >> 1;

#pragma unroll
        for (int nt = 0; nt < 8; ++nt) {
            f32x4 acc = {0.f, 0.f, 0.f, 0.f};
            acc = __builtin_amdgcn_mfma_f32_16x16x32_f16(a3[0], b3f[nt][0], acc, 0, 0, 0);
            acc = __builtin_amdgcn_mfma_f32_16x16x32_f16(a3[1], b3f[nt][1], acc, 0, 0, 0);
            // lane: rows pt-local = q*4 + reg, col o = nt*16 + m16
            float m0 = fmaxf(fmaxf(acc[0] + madd[0], acc[1] + madd[1]),
                             fmaxf(acc[2] + madd[2], acc[3] + madd[3]));
            vmax[nt][v] = fmaxf(vmax[nt][v], m0);
        }
    }

    // ---- epilogue: cross-quad max, bias, store ----
#pragma unroll
    for (int nt = 0; nt < 8; ++nt) {
#pragma unroll
        for (int v = 0; v < 2; ++v) {
            float t = vmax[nt][v];
            t = fmaxf(t, __shfl_xor(t, 16));
            t = fmaxf(t, __shfl_xor(t, 32));
            if (q == v)
                out[(size_t)(voxA + v) * ODIM + nt * 16 + m16] = t + b3r[nt];
        }
    }
}

extern "C" void kernel_launch(void* const* d_in, const int* in_sizes, int n_in,
                              void* d_out, int out_size, void* d_ws, size_t ws_size,
                              hipStream_t stream) {
    const float* vf  = (const float*)d_in[0];
    const int*   vnp = (const int*)d_in[1];
    const float* W1  = (const float*)d_in[2];
    const float* b1  = (const float*)d_in[3];
    const float* g1  = (const float*)d_in[4];
    const float* be1 = (const float*)d_in[5];
    const float* m1  = (const float*)d_in[6];
    const float* v1  = (const float*)d_in[7];
    const float* W2  = (const float*)d_in[8];
    const float* b2  = (const float*)d_in[9];
    const float* g2  = (const float*)d_in[10];
    const float* be2 = (const float*)d_in[11];
    const float* m2  = (const float*)d_in[12];
    const float* v2  = (const float*)d_in[13];
    const float* W3  = (const float*)d_in[14];
    const float* b3  = (const float*)d_in[15];
    float* out = (float*)d_out;

    const int blocks = (NVOX * PPTS) / 256;   // 6250 blocks, 4 waves each, 64 pts/wave
    vfe_mfma<<<blocks, 256, 0, stream>>>(vf, vnp, W1, b1, g1, be1, m1, v1,
                                         W2, b2, g2, be2, m2, v2, W3, b3, out);
}